// Round 11
// baseline (153.396 us; speedup 1.0000x reference)
//
#include <hip/hip_runtime.h>

#define N_NODES 50000
#define N_EDGES 800000
#define IN_DIM  128
#define HID_DIM 64
#define OUT_DIM 64
#define NB_NODE 196          // ceil(50000/256)
#define SCAT_BLOCKS 782      // 800000 / (256*4) rounded up
#define GEMM1_BLOCKS 3125    // 50000/16
#define AGG_BLOCKS 3125      // 50000/16

typedef _Float16 half4v __attribute__((ext_vector_type(4)));
typedef float float4v __attribute__((ext_vector_type(4)));

__device__ __forceinline__ void f4addh(float4& a, const half4v v) {
    a.x += (float)v.x; a.y += (float)v.y; a.z += (float)v.z; a.w += (float)v.w;
}

// ---------------- CSR build ----------------
__global__ void k_zero_counts(int* __restrict__ counts) {
    int i = blockIdx.x * blockDim.x + threadIdx.x;
    if (i < N_NODES) counts[i] = 0;
}

// single-pass histogram, int4 loads (4 independent atomics in flight per thread)
__global__ void k_count(const int* __restrict__ dst, int* __restrict__ counts) {
    const int e0 = (blockIdx.x * blockDim.x + threadIdx.x) * 4;
    if (e0 + 3 < N_EDGES) {          // N_EDGES % 4 == 0
        const int4 d4 = *reinterpret_cast<const int4*>(&dst[e0]);
        atomicAdd(&counts[d4.x], 1);
        atomicAdd(&counts[d4.y], 1);
        atomicAdd(&counts[d4.z], 1);
        atomicAdd(&counts[d4.w], 1);
    }
}

__global__ void k_scan_local(const int* __restrict__ counts, int* __restrict__ ex,
                             int* __restrict__ bsum) {
    __shared__ int s[256];
    const int t = threadIdx.x;
    const int i = blockIdx.x * 256 + t;
    int v = (i < N_NODES) ? counts[i] : 0;
    s[t] = v;
    __syncthreads();
    for (int off = 1; off < 256; off <<= 1) {
        int add = (t >= off) ? s[t - off] : 0;
        __syncthreads();
        s[t] += add;
        __syncthreads();
    }
    if (i < N_NODES) ex[i] = s[t] - v;
    if (t == 255) bsum[blockIdx.x] = s[255];
}

__global__ void k_scan_bsum(int* __restrict__ bsum) {
    __shared__ int s[256];
    const int t = threadIdx.x;
    int v = (t < NB_NODE) ? bsum[t] : 0;
    s[t] = v;
    __syncthreads();
    for (int off = 1; off < 256; off <<= 1) {
        int add = (t >= off) ? s[t - off] : 0;
        __syncthreads();
        s[t] += add;
        __syncthreads();
    }
    if (t < NB_NODE) bsum[t] = s[t] - v;  // exclusive
}

__global__ void k_finalize(const int* __restrict__ counts, const int* __restrict__ ex,
                           const int* __restrict__ bsum, int* __restrict__ offsets,
                           int* __restrict__ cursor, float* __restrict__ dinv) {
    int i = blockIdx.x * blockDim.x + threadIdx.x;
    if (i >= N_NODES) return;
    int o = ex[i] + bsum[blockIdx.x];
    offsets[i] = o;
    cursor[i] = o;
    dinv[i] = rsqrtf((float)(counts[i] + 1));  // +1: self-loop
}

// ---------------- fused: batched scatter (blocks < SCAT_BLOCKS) || gemm1 ------------
// Scatter: 4 edges/thread, int4 loads, 4 INDEPENDENT atomicAdd chains in flight.
__global__ __launch_bounds__(256) void k_scatter_gemm1(
        const int* __restrict__ src, const int* __restrict__ dst,
        int* __restrict__ cursor, unsigned short* __restrict__ csr,
        const float* __restrict__ x, const float* __restrict__ W1,
        const float* __restrict__ dinv, _Float16* __restrict__ h1s) {
    __shared__ float xs[16][IN_DIM];   // 8 KB (gemm1 role only)
    const int bid = blockIdx.x;
    if (bid < SCAT_BLOCKS) {
        const int e0 = (bid * 256 + threadIdx.x) * 4;
        if (e0 + 3 < N_EDGES) {        // N_EDGES % 4 == 0 -> exact coverage
            const int4 d4 = *reinterpret_cast<const int4*>(&dst[e0]);
            const int4 s4 = *reinterpret_cast<const int4*>(&src[e0]);
            const int p0 = atomicAdd(&cursor[d4.x], 1);
            const int p1 = atomicAdd(&cursor[d4.y], 1);
            const int p2 = atomicAdd(&cursor[d4.z], 1);
            const int p3 = atomicAdd(&cursor[d4.w], 1);
            csr[p0] = (unsigned short)s4.x;
            csr[p1] = (unsigned short)s4.y;
            csr[p2] = (unsigned short)s4.z;
            csr[p3] = (unsigned short)s4.w;
        }
        return;
    }
    // ---- gemm1 role: 16 nodes/block, 4 nodes/thread ----
    const int t = threadIdx.x;
    const int wave = t >> 6;
    const int lane = t & 63;
    const long base = (long)(bid - SCAT_BLOCKS) * 16;
    {
        float4* xsv = reinterpret_cast<float4*>(&xs[0][0]);
        const float4* xv = reinterpret_cast<const float4*>(&x[base * IN_DIM]);
        xsv[t]       = xv[t];
        xsv[t + 256] = xv[t + 256];
    }
    __syncthreads();
    const int n0 = wave * 4, n1 = n0 + 1, n2 = n0 + 2, n3 = n0 + 3;
    float a0 = 0.f, a1 = 0.f, a2 = 0.f, a3 = 0.f;
#pragma unroll 8
    for (int k = 0; k < IN_DIM; ++k) {
        const float wv = W1[k * HID_DIM + lane];
        a0 = fmaf(xs[n0][k], wv, a0);
        a1 = fmaf(xs[n1][k], wv, a1);
        a2 = fmaf(xs[n2][k], wv, a2);
        a3 = fmaf(xs[n3][k], wv, a3);
    }
    h1s[(base + n0) * HID_DIM + lane] = (_Float16)(a0 * dinv[base + n0]);
    h1s[(base + n1) * HID_DIM + lane] = (_Float16)(a1 * dinv[base + n1]);
    h1s[(base + n2) * HID_DIM + lane] = (_Float16)(a2 * dinv[base + n2]);
    h1s[(base + n3) * HID_DIM + lane] = (_Float16)(a3 * dinv[base + n3]);
}

// ---------------- gather core: one 16-lane group owns one node, 8-deep pipeline ------
__device__ __forceinline__ float4 gather_node(
        const unsigned short* __restrict__ csr, const _Float16* __restrict__ h,
        int n, int beg, int cnt, int sub) {
    float4 a0 = {0,0,0,0}, a1 = {0,0,0,0}, a2 = {0,0,0,0}, a3 = {0,0,0,0};
    int e = 0;
    for (; e + 8 <= cnt; e += 8) {
        int idx[8];
#pragma unroll
        for (int j = 0; j < 8; ++j) idx[j] = csr[beg + e + j];
        half4v v[8];
#pragma unroll
        for (int j = 0; j < 8; ++j)
            v[j] = *reinterpret_cast<const half4v*>(&h[(long)idx[j] * 64 + sub * 4]);
        f4addh(a0, v[0]); f4addh(a1, v[1]); f4addh(a2, v[2]); f4addh(a3, v[3]);
        f4addh(a0, v[4]); f4addh(a1, v[5]); f4addh(a2, v[6]); f4addh(a3, v[7]);
    }
    if (e + 4 <= cnt) {
        int idx[4];
#pragma unroll
        for (int j = 0; j < 4; ++j) idx[j] = csr[beg + e + j];
        half4v v[4];
#pragma unroll
        for (int j = 0; j < 4; ++j)
            v[j] = *reinterpret_cast<const half4v*>(&h[(long)idx[j] * 64 + sub * 4]);
        f4addh(a0, v[0]); f4addh(a1, v[1]); f4addh(a2, v[2]); f4addh(a3, v[3]);
        e += 4;
    }
    for (; e < cnt; ++e)
        f4addh(a0, *reinterpret_cast<const half4v*>(&h[(long)csr[beg + e] * 64 + sub * 4]));
    f4addh(a1, *reinterpret_cast<const half4v*>(&h[(long)n * 64 + sub * 4]));  // self-loop
    float4 a;
    a.x = (a0.x + a1.x) + (a2.x + a3.x);
    a.y = (a0.y + a1.y) + (a2.y + a3.y);
    a.z = (a0.z + a1.z) + (a2.z + a3.z);
    a.w = (a0.w + a1.w) + (a2.w + a3.w);
    return a;
}

// ---------------- fused: agg layer1 + bias + ReLU + GEMM2 + pre-scale ---------------
__global__ __launch_bounds__(256) void k_agg1_fused(
        const unsigned short* __restrict__ csr, const int* __restrict__ offsets,
        const int* __restrict__ counts, const float* __restrict__ dinv,
        const _Float16* __restrict__ h1s, const float* __restrict__ b1,
        const float* __restrict__ W2, _Float16* __restrict__ h3s) {
    __shared__ float rs[16][HID_DIM];   // 4 KB
    const int g = threadIdx.x >> 4;
    const int sub = threadIdx.x & 15;
    const long nbase = (long)blockIdx.x * 16;
    const int n = (int)nbase + g;
    const int beg = offsets[n];
    const int cnt = counts[n];
    float4 a = gather_node(csr, h1s, n, beg, cnt, sub);
    const float di = dinv[n];
    const float4 bv = *reinterpret_cast<const float4*>(&b1[sub * 4]);
    float4 r;
    r.x = fmaxf(a.x * di + bv.x, 0.0f);
    r.y = fmaxf(a.y * di + bv.y, 0.0f);
    r.z = fmaxf(a.z * di + bv.z, 0.0f);
    r.w = fmaxf(a.w * di + bv.w, 0.0f);
    *reinterpret_cast<float4*>(&rs[g][sub * 4]) = r;
    __syncthreads();
    // GEMM phase: wave w computes nodes 4w..4w+3
    const int wave = threadIdx.x >> 6;
    const int lane = threadIdx.x & 63;
    float acc[4] = {0.f, 0.f, 0.f, 0.f};
#pragma unroll 4
    for (int k = 0; k < HID_DIM; ++k) {
        const float wv = W2[k * OUT_DIM + lane];
#pragma unroll
        for (int m = 0; m < 4; ++m)
            acc[m] = fmaf(rs[wave * 4 + m][k], wv, acc[m]);
    }
#pragma unroll
    for (int m = 0; m < 4; ++m) {
        const long node = nbase + wave * 4 + m;
        h3s[node * 64 + lane] = (_Float16)(acc[m] * dinv[node]);
    }
}

// ---------------- final aggregation (non-temporal dout stores) ----------------------
__global__ __launch_bounds__(256) void k_agg2(
        const unsigned short* __restrict__ csr, const int* __restrict__ offsets,
        const int* __restrict__ counts, const float* __restrict__ dinv,
        const _Float16* __restrict__ h3s, const float* __restrict__ b2,
        float* __restrict__ dout) {
    const int g = threadIdx.x >> 4;
    const int sub = threadIdx.x & 15;
    const int n = blockIdx.x * 16 + g;
    const int beg = offsets[n];
    const int cnt = counts[n];
    float4 a = gather_node(csr, h3s, n, beg, cnt, sub);
    const float di = dinv[n];
    const float4 bv = *reinterpret_cast<const float4*>(&b2[sub * 4]);
    float4v r;
    r.x = a.x * di + bv.x;
    r.y = a.y * di + bv.y;
    r.z = a.z * di + bv.z;
    r.w = a.w * di + bv.w;
    // dout is never re-read: bypass caches to protect the h3s gather working set
    __builtin_nontemporal_store(r, reinterpret_cast<float4v*>(&dout[(long)n * 64 + sub * 4]));
}

extern "C" void kernel_launch(void* const* d_in, const int* in_sizes, int n_in,
                              void* d_out, int out_size, void* d_ws, size_t ws_size,
                              hipStream_t stream) {
    const float* x  = (const float*)d_in[0];
    const int*   ei = (const int*)d_in[1];          // [2, N_EDGES]
    const float* W1 = (const float*)d_in[2];
    const float* b1 = (const float*)d_in[3];
    const float* W2 = (const float*)d_in[4];
    const float* b2 = (const float*)d_in[5];
    float* dout = (float*)d_out;

    const int* src = ei;
    const int* dst = ei + N_EDGES;

    char* w = (char*)d_ws;
    int*            counts  = (int*)w;            w += 50176 * 4;
    int*            ex      = (int*)w;            w += 50176 * 4;
    int*            bsum    = (int*)w;            w += 256 * 4;
    int*            offsets = (int*)w;            w += 50176 * 4;
    int*            cursor  = (int*)w;            w += 50176 * 4;
    float*          dinv    = (float*)w;          w += 50176 * 4;
    unsigned short* csr     = (unsigned short*)w; w += (long)N_EDGES * 2;
    _Float16*       h1s     = (_Float16*)w;       w += (long)N_NODES * 64 * 2;
    _Float16*       h3s     = (_Float16*)w;

    k_zero_counts<<<NB_NODE, 256, 0, stream>>>(counts);
    k_count<<<782, 256, 0, stream>>>(dst, counts);
    k_scan_local<<<NB_NODE, 256, 0, stream>>>(counts, ex, bsum);
    k_scan_bsum<<<1, 256, 0, stream>>>(bsum);
    k_finalize<<<NB_NODE, 256, 0, stream>>>(counts, ex, bsum, offsets, cursor, dinv);

    k_scatter_gemm1<<<SCAT_BLOCKS + GEMM1_BLOCKS, 256, 0, stream>>>(
        src, dst, cursor, csr, x, W1, dinv, h1s);

    k_agg1_fused<<<AGG_BLOCKS, 256, 0, stream>>>(csr, offsets, counts, dinv, h1s, b1, W2, h3s);
    k_agg2<<<AGG_BLOCKS, 256, 0, stream>>>(csr, offsets, counts, dinv, h3s, b2, dout);
}

// Round 12
// 136.435 us; speedup vs baseline: 1.1243x; 1.1243x over previous
//
#include <hip/hip_runtime.h>

#define N_NODES 50000
#define N_EDGES 800000
#define IN_DIM  128
#define HID_DIM 64
#define OUT_DIM 64
#define NB_NODE 196          // ceil(50000/256) -- blocks over nodes, also #buckets
#define NBUCK   196          // bucket b covers nodes [b*256, b*256+256)
#define EDGE_BLOCKS 782      // ceil(800000 / (256*4))
#define GEMM1_BLOCKS 3125    // 50000/16
#define AGG_BLOCKS 3125      // 50000/16
#define SBUF_CAP 6144        // staged csr segment capacity (avg 4096, max ~4400)

typedef _Float16 half4v __attribute__((ext_vector_type(4)));
typedef float float4v __attribute__((ext_vector_type(4)));

__device__ __forceinline__ void f4addh(float4& a, const half4v v) {
    a.x += (float)v.x; a.y += (float)v.y; a.z += (float)v.z; a.w += (float)v.w;
}

// ---------------- kA: bucket histogram (LDS -> 1 global atomic per block-bucket) ----
__global__ __launch_bounds__(256) void k_bucket_histo(
        const int* __restrict__ dst, int* __restrict__ bucket_counts) {
    __shared__ int histo[256];
    histo[threadIdx.x] = 0;
    __syncthreads();
    const int e0 = (blockIdx.x * 256 + threadIdx.x) * 4;
    if (e0 + 3 < N_EDGES) {
        const int4 d4 = *reinterpret_cast<const int4*>(&dst[e0]);
        atomicAdd(&histo[d4.x >> 8], 1);
        atomicAdd(&histo[d4.y >> 8], 1);
        atomicAdd(&histo[d4.z >> 8], 1);
        atomicAdd(&histo[d4.w >> 8], 1);
    }
    __syncthreads();
    const int h = histo[threadIdx.x];
    if (h > 0) atomicAdd(&bucket_counts[threadIdx.x], h);
}

// ---------------- scanB: exclusive scan of 256 bucket counts ----------------
__global__ void k_scan_buckets(const int* __restrict__ bucket_counts,
                               int* __restrict__ boff, int* __restrict__ bcur) {
    __shared__ int s[256];
    const int t = threadIdx.x;
    const int v = bucket_counts[t];
    s[t] = v;
    __syncthreads();
    for (int off = 1; off < 256; off <<= 1) {
        int add = (t >= off) ? s[t - off] : 0;
        __syncthreads();
        s[t] += add;
        __syncthreads();
    }
    boff[t] = s[t] - v;
    bcur[t] = s[t] - v;
}

// ---------------- kB: bucket scatter (LDS histo + per-block reservation) ------------
// ebuf entry: src | (dst&255)<<16
__global__ __launch_bounds__(256) void k_bucket_scatter(
        const int* __restrict__ src, const int* __restrict__ dst,
        int* __restrict__ bcur, unsigned int* __restrict__ ebuf) {
    __shared__ int histo[256];
    __shared__ int cur[256];
    histo[threadIdx.x] = 0;
    __syncthreads();
    const int e0 = (blockIdx.x * 256 + threadIdx.x) * 4;
    int4 d4 = {0, 0, 0, 0}, s4 = {0, 0, 0, 0};
    const bool valid = (e0 + 3 < N_EDGES);
    if (valid) {
        d4 = *reinterpret_cast<const int4*>(&dst[e0]);
        s4 = *reinterpret_cast<const int4*>(&src[e0]);
        atomicAdd(&histo[d4.x >> 8], 1);
        atomicAdd(&histo[d4.y >> 8], 1);
        atomicAdd(&histo[d4.z >> 8], 1);
        atomicAdd(&histo[d4.w >> 8], 1);
    }
    __syncthreads();
    {
        const int h = histo[threadIdx.x];
        cur[threadIdx.x] = (h > 0) ? atomicAdd(&bcur[threadIdx.x], h) : 0;
    }
    __syncthreads();
    if (valid) {
        int p;
        p = atomicAdd(&cur[d4.x >> 8], 1);
        ebuf[p] = (unsigned int)s4.x | ((unsigned int)(d4.x & 255) << 16);
        p = atomicAdd(&cur[d4.y >> 8], 1);
        ebuf[p] = (unsigned int)s4.y | ((unsigned int)(d4.y & 255) << 16);
        p = atomicAdd(&cur[d4.z >> 8], 1);
        ebuf[p] = (unsigned int)s4.z | ((unsigned int)(d4.z & 255) << 16);
        p = atomicAdd(&cur[d4.w >> 8], 1);
        ebuf[p] = (unsigned int)s4.w | ((unsigned int)(d4.w & 255) << 16);
    }
}

// ---------------- kC: per-bucket node counts (LDS counters) ----------------
__global__ __launch_bounds__(256) void k_node_counts(
        const unsigned int* __restrict__ ebuf, const int* __restrict__ boff,
        int* __restrict__ counts) {
    __shared__ int cnt[256];
    cnt[threadIdx.x] = 0;
    __syncthreads();
    const int nb = blockIdx.x;
    const int beg = boff[nb];
    const int end = boff[nb + 1];
    for (int e = beg + threadIdx.x; e < end; e += 256)
        atomicAdd(&cnt[ebuf[e] >> 16], 1);
    __syncthreads();
    const int node = nb * 256 + threadIdx.x;
    if (node < N_NODES) counts[node] = cnt[threadIdx.x];
}

// ---------------- node-level scans (unchanged) ----------------
__global__ void k_scan_local(const int* __restrict__ counts, int* __restrict__ ex,
                             int* __restrict__ bsum) {
    __shared__ int s[256];
    const int t = threadIdx.x;
    const int i = blockIdx.x * 256 + t;
    int v = (i < N_NODES) ? counts[i] : 0;
    s[t] = v;
    __syncthreads();
    for (int off = 1; off < 256; off <<= 1) {
        int add = (t >= off) ? s[t - off] : 0;
        __syncthreads();
        s[t] += add;
        __syncthreads();
    }
    if (i < N_NODES) ex[i] = s[t] - v;
    if (t == 255) bsum[blockIdx.x] = s[255];
}

__global__ void k_scan_bsum(int* __restrict__ bsum) {
    __shared__ int s[256];
    const int t = threadIdx.x;
    int v = (t < NB_NODE) ? bsum[t] : 0;
    s[t] = v;
    __syncthreads();
    for (int off = 1; off < 256; off <<= 1) {
        int add = (t >= off) ? s[t - off] : 0;
        __syncthreads();
        s[t] += add;
        __syncthreads();
    }
    if (t < NB_NODE) bsum[t] = s[t] - v;  // exclusive
}

__global__ void k_finalize(const int* __restrict__ counts, const int* __restrict__ ex,
                           const int* __restrict__ bsum, int* __restrict__ offsets,
                           float* __restrict__ dinv) {
    int i = blockIdx.x * blockDim.x + threadIdx.x;
    if (i >= N_NODES) return;
    offsets[i] = ex[i] + bsum[blockIdx.x];
    dinv[i] = rsqrtf((float)(counts[i] + 1));  // +1: self-loop
}

// ---------------- kD || gemm1: per-bucket CSR placement (LDS-staged) + gemm1 --------
__global__ __launch_bounds__(256) void k_place_gemm1(
        const unsigned int* __restrict__ ebuf, const int* __restrict__ boff,
        const int* __restrict__ offsets, unsigned short* __restrict__ csr,
        const float* __restrict__ x, const float* __restrict__ W1,
        const float* __restrict__ dinv, _Float16* __restrict__ h1s) {
    __shared__ union {
        float xs[16][IN_DIM];                          // gemm1 role (8 KB)
        struct {
            int offs[256];
            int rank[256];
            unsigned short sbuf[SBUF_CAP];
        } p;                                           // place role (14 KB)
    } sm;
    const int bid = blockIdx.x;
    if (bid < NBUCK) {
        // ---- placement role ----
        const int nb = bid;
        const int nbase = nb * 256;
        const int ebeg = boff[nb];
        const int eend = boff[nb + 1];
        const int seglen = eend - ebeg;   // == csr segment length for this bucket
        const int cbase = offsets[nbase];
        {
            const int node = nbase + threadIdx.x;
            sm.p.offs[threadIdx.x] = ((node < N_NODES) ? offsets[node] : N_EDGES) - cbase;
            sm.p.rank[threadIdx.x] = 0;
        }
        __syncthreads();
        const bool staged = (seglen <= SBUF_CAP);
        for (int e = ebeg + threadIdx.x; e < eend; e += 256) {
            const unsigned int u = ebuf[e];
            const unsigned short s = (unsigned short)(u & 0xFFFF);
            const int dl = (int)(u >> 16);
            const int r = atomicAdd(&sm.p.rank[dl], 1);
            const int lp = sm.p.offs[dl] + r;
            if (staged) sm.p.sbuf[lp] = s;
            else        csr[cbase + lp] = s;
        }
        __syncthreads();
        if (staged) {
            for (int i = threadIdx.x; i < seglen; i += 256)
                csr[cbase + i] = sm.p.sbuf[i];
        }
        return;
    }
    // ---- gemm1 role: 16 nodes/block, 4 nodes/thread ----
    const int t = threadIdx.x;
    const int wave = t >> 6;
    const int lane = t & 63;
    const long base = (long)(bid - NBUCK) * 16;
    {
        float4* xsv = reinterpret_cast<float4*>(&sm.xs[0][0]);
        const float4* xv = reinterpret_cast<const float4*>(&x[base * IN_DIM]);
        xsv[t]       = xv[t];
        xsv[t + 256] = xv[t + 256];
    }
    __syncthreads();
    const int n0 = wave * 4, n1 = n0 + 1, n2 = n0 + 2, n3 = n0 + 3;
    float a0 = 0.f, a1 = 0.f, a2 = 0.f, a3 = 0.f;
#pragma unroll 8
    for (int k = 0; k < IN_DIM; ++k) {
        const float wv = W1[k * HID_DIM + lane];
        a0 = fmaf(sm.xs[n0][k], wv, a0);
        a1 = fmaf(sm.xs[n1][k], wv, a1);
        a2 = fmaf(sm.xs[n2][k], wv, a2);
        a3 = fmaf(sm.xs[n3][k], wv, a3);
    }
    h1s[(base + n0) * HID_DIM + lane] = (_Float16)(a0 * dinv[base + n0]);
    h1s[(base + n1) * HID_DIM + lane] = (_Float16)(a1 * dinv[base + n1]);
    h1s[(base + n2) * HID_DIM + lane] = (_Float16)(a2 * dinv[base + n2]);
    h1s[(base + n3) * HID_DIM + lane] = (_Float16)(a3 * dinv[base + n3]);
}

// ---------------- gather core: one 16-lane group owns one node, 8-deep pipeline ------
__device__ __forceinline__ float4 gather_node(
        const unsigned short* __restrict__ csr, const _Float16* __restrict__ h,
        int n, int beg, int cnt, int sub) {
    float4 a0 = {0,0,0,0}, a1 = {0,0,0,0}, a2 = {0,0,0,0}, a3 = {0,0,0,0};
    int e = 0;
    for (; e + 8 <= cnt; e += 8) {
        int idx[8];
#pragma unroll
        for (int j = 0; j < 8; ++j) idx[j] = csr[beg + e + j];
        half4v v[8];
#pragma unroll
        for (int j = 0; j < 8; ++j)
            v[j] = *reinterpret_cast<const half4v*>(&h[(long)idx[j] * 64 + sub * 4]);
        f4addh(a0, v[0]); f4addh(a1, v[1]); f4addh(a2, v[2]); f4addh(a3, v[3]);
        f4addh(a0, v[4]); f4addh(a1, v[5]); f4addh(a2, v[6]); f4addh(a3, v[7]);
    }
    if (e + 4 <= cnt) {
        int idx[4];
#pragma unroll
        for (int j = 0; j < 4; ++j) idx[j] = csr[beg + e + j];
        half4v v[4];
#pragma unroll
        for (int j = 0; j < 4; ++j)
            v[j] = *reinterpret_cast<const half4v*>(&h[(long)idx[j] * 64 + sub * 4]);
        f4addh(a0, v[0]); f4addh(a1, v[1]); f4addh(a2, v[2]); f4addh(a3, v[3]);
        e += 4;
    }
    for (; e < cnt; ++e)
        f4addh(a0, *reinterpret_cast<const half4v*>(&h[(long)csr[beg + e] * 64 + sub * 4]));
    f4addh(a1, *reinterpret_cast<const half4v*>(&h[(long)n * 64 + sub * 4]));  // self-loop
    float4 a;
    a.x = (a0.x + a1.x) + (a2.x + a3.x);
    a.y = (a0.y + a1.y) + (a2.y + a3.y);
    a.z = (a0.z + a1.z) + (a2.z + a3.z);
    a.w = (a0.w + a1.w) + (a2.w + a3.w);
    return a;
}

// ---------------- fused: agg layer1 + bias + ReLU + GEMM2 + pre-scale ---------------
__global__ __launch_bounds__(256) void k_agg1_fused(
        const unsigned short* __restrict__ csr, const int* __restrict__ offsets,
        const int* __restrict__ counts, const float* __restrict__ dinv,
        const _Float16* __restrict__ h1s, const float* __restrict__ b1,
        const float* __restrict__ W2, _Float16* __restrict__ h3s) {
    __shared__ float rs[16][HID_DIM];   // 4 KB
    const int g = threadIdx.x >> 4;
    const int sub = threadIdx.x & 15;
    const long nbase = (long)blockIdx.x * 16;
    const int n = (int)nbase + g;
    const int beg = offsets[n];
    const int cnt = counts[n];
    float4 a = gather_node(csr, h1s, n, beg, cnt, sub);
    const float di = dinv[n];
    const float4 bv = *reinterpret_cast<const float4*>(&b1[sub * 4]);
    float4 r;
    r.x = fmaxf(a.x * di + bv.x, 0.0f);
    r.y = fmaxf(a.y * di + bv.y, 0.0f);
    r.z = fmaxf(a.z * di + bv.z, 0.0f);
    r.w = fmaxf(a.w * di + bv.w, 0.0f);
    *reinterpret_cast<float4*>(&rs[g][sub * 4]) = r;
    __syncthreads();
    // GEMM phase: wave w computes nodes 4w..4w+3
    const int wave = threadIdx.x >> 6;
    const int lane = threadIdx.x & 63;
    float acc[4] = {0.f, 0.f, 0.f, 0.f};
#pragma unroll 4
    for (int k = 0; k < HID_DIM; ++k) {
        const float wv = W2[k * OUT_DIM + lane];
#pragma unroll
        for (int m = 0; m < 4; ++m)
            acc[m] = fmaf(rs[wave * 4 + m][k], wv, acc[m]);
    }
#pragma unroll
    for (int m = 0; m < 4; ++m) {
        const long node = nbase + wave * 4 + m;
        h3s[node * 64 + lane] = (_Float16)(acc[m] * dinv[node]);
    }
}

// ---------------- final aggregation (non-temporal dout stores) ----------------------
__global__ __launch_bounds__(256) void k_agg2(
        const unsigned short* __restrict__ csr, const int* __restrict__ offsets,
        const int* __restrict__ counts, const float* __restrict__ dinv,
        const _Float16* __restrict__ h3s, const float* __restrict__ b2,
        float* __restrict__ dout) {
    const int g = threadIdx.x >> 4;
    const int sub = threadIdx.x & 15;
    const int n = blockIdx.x * 16 + g;
    const int beg = offsets[n];
    const int cnt = counts[n];
    float4 a = gather_node(csr, h3s, n, beg, cnt, sub);
    const float di = dinv[n];
    const float4 bv = *reinterpret_cast<const float4*>(&b2[sub * 4]);
    float4v r;
    r.x = a.x * di + bv.x;
    r.y = a.y * di + bv.y;
    r.z = a.z * di + bv.z;
    r.w = a.w * di + bv.w;
    __builtin_nontemporal_store(r, reinterpret_cast<float4v*>(&dout[(long)n * 64 + sub * 4]));
}

// ---------------- zero init for bucket counters ----------------
__global__ void k_zero_buckets(int* __restrict__ bucket_counts) {
    bucket_counts[threadIdx.x] = 0;
}

extern "C" void kernel_launch(void* const* d_in, const int* in_sizes, int n_in,
                              void* d_out, int out_size, void* d_ws, size_t ws_size,
                              hipStream_t stream) {
    const float* x  = (const float*)d_in[0];
    const int*   ei = (const int*)d_in[1];          // [2, N_EDGES]
    const float* W1 = (const float*)d_in[2];
    const float* b1 = (const float*)d_in[3];
    const float* W2 = (const float*)d_in[4];
    const float* b2 = (const float*)d_in[5];
    float* dout = (float*)d_out;

    const int* src = ei;
    const int* dst = ei + N_EDGES;

    char* w = (char*)d_ws;
    int*            counts   = (int*)w;            w += 50176 * 4;
    int*            ex       = (int*)w;            w += 50176 * 4;
    int*            bsum     = (int*)w;            w += 256 * 4;
    int*            offsets  = (int*)w;            w += 50176 * 4;
    float*          dinv     = (float*)w;          w += 50176 * 4;
    int*            bcnt     = (int*)w;            w += 256 * 4;
    int*            boff     = (int*)w;            w += 256 * 4;
    int*            bcur     = (int*)w;            w += 256 * 4;
    unsigned int*   ebuf     = (unsigned int*)w;   w += (long)N_EDGES * 4;
    unsigned short* csr      = (unsigned short*)w; w += (long)N_EDGES * 2;
    _Float16*       h1s      = (_Float16*)w;       w += (long)N_NODES * 64 * 2;
    _Float16*       h3s      = (_Float16*)w;

    // CSR build via two-level LDS counting sort (no fine-grained global atomics)
    k_zero_buckets<<<1, 256, 0, stream>>>(bcnt);
    k_bucket_histo<<<EDGE_BLOCKS, 256, 0, stream>>>(dst, bcnt);
    k_scan_buckets<<<1, 256, 0, stream>>>(bcnt, boff, bcur);
    k_bucket_scatter<<<EDGE_BLOCKS, 256, 0, stream>>>(src, dst, bcur, ebuf);
    k_node_counts<<<NBUCK, 256, 0, stream>>>(ebuf, boff, counts);
    k_scan_local<<<NB_NODE, 256, 0, stream>>>(counts, ex, bsum);
    k_scan_bsum<<<1, 256, 0, stream>>>(bsum);
    k_finalize<<<NB_NODE, 256, 0, stream>>>(counts, ex, bsum, offsets, dinv);

    k_place_gemm1<<<NBUCK + GEMM1_BLOCKS, 256, 0, stream>>>(
        ebuf, boff, offsets, csr, x, W1, dinv, h1s);

    k_agg1_fused<<<AGG_BLOCKS, 256, 0, stream>>>(csr, offsets, counts, dinv, h1s, b1, W2, h3s);
    k_agg2<<<AGG_BLOCKS, 256, 0, stream>>>(csr, offsets, counts, dinv, h3s, b2, dout);
}

// Round 13
// 129.537 us; speedup vs baseline: 1.1842x; 1.0532x over previous
//
#include <hip/hip_runtime.h>

#define N_NODES 50000
#define N_EDGES 800000
#define IN_DIM  128
#define HID_DIM 64
#define OUT_DIM 64
#define NBUCK   196          // bucket b covers nodes [b*256, b*256+256)
#define EDGE_BLOCKS 782      // ceil(800000 / (256*4))
#define GEMM1_BLOCKS 3125    // 50000/16
#define AGG_BLOCKS 3125      // 50000/16
#define SBUF_CAP 6144        // staged csr segment capacity (avg 4096)

typedef _Float16 half4v __attribute__((ext_vector_type(4)));
typedef float float4v __attribute__((ext_vector_type(4)));

__device__ __forceinline__ void f4addh(float4& a, const half4v v) {
    a.x += (float)v.x; a.y += (float)v.y; a.z += (float)v.z; a.w += (float)v.w;
}

// ---------------- zero init for bucket counters ----------------
__global__ void k_zero_buckets(int* __restrict__ bucket_counts) {
    bucket_counts[threadIdx.x] = 0;
}

// ---------------- kA: bucket histogram (LDS -> 1 global atomic per block-bucket) ----
__global__ __launch_bounds__(256) void k_bucket_histo(
        const int* __restrict__ dst, int* __restrict__ bucket_counts) {
    __shared__ int histo[256];
    histo[threadIdx.x] = 0;
    __syncthreads();
    const int e0 = (blockIdx.x * 256 + threadIdx.x) * 4;
    if (e0 + 3 < N_EDGES) {
        const int4 d4 = *reinterpret_cast<const int4*>(&dst[e0]);
        atomicAdd(&histo[d4.x >> 8], 1);
        atomicAdd(&histo[d4.y >> 8], 1);
        atomicAdd(&histo[d4.z >> 8], 1);
        atomicAdd(&histo[d4.w >> 8], 1);
    }
    __syncthreads();
    const int h = histo[threadIdx.x];
    if (h > 0) atomicAdd(&bucket_counts[threadIdx.x], h);
}

// ---------------- scanB: exclusive scan of 256 bucket counts ----------------
__global__ void k_scan_buckets(const int* __restrict__ bucket_counts,
                               int* __restrict__ boff, int* __restrict__ bcur) {
    __shared__ int s[256];
    const int t = threadIdx.x;
    const int v = bucket_counts[t];
    s[t] = v;
    __syncthreads();
    for (int off = 1; off < 256; off <<= 1) {
        int add = (t >= off) ? s[t - off] : 0;
        __syncthreads();
        s[t] += add;
        __syncthreads();
    }
    boff[t] = s[t] - v;
    bcur[t] = s[t] - v;
}

// ---------------- kB: bucket scatter (LDS histo + per-block reservation) ------------
// ebuf entry: src | (dst&255)<<16
__global__ __launch_bounds__(256) void k_bucket_scatter(
        const int* __restrict__ src, const int* __restrict__ dst,
        int* __restrict__ bcur, unsigned int* __restrict__ ebuf) {
    __shared__ int histo[256];
    __shared__ int cur[256];
    histo[threadIdx.x] = 0;
    __syncthreads();
    const int e0 = (blockIdx.x * 256 + threadIdx.x) * 4;
    int4 d4 = {0, 0, 0, 0}, s4 = {0, 0, 0, 0};
    const bool valid = (e0 + 3 < N_EDGES);
    if (valid) {
        d4 = *reinterpret_cast<const int4*>(&dst[e0]);
        s4 = *reinterpret_cast<const int4*>(&src[e0]);
        atomicAdd(&histo[d4.x >> 8], 1);
        atomicAdd(&histo[d4.y >> 8], 1);
        atomicAdd(&histo[d4.z >> 8], 1);
        atomicAdd(&histo[d4.w >> 8], 1);
    }
    __syncthreads();
    {
        const int h = histo[threadIdx.x];
        cur[threadIdx.x] = (h > 0) ? atomicAdd(&bcur[threadIdx.x], h) : 0;
    }
    __syncthreads();
    if (valid) {
        int p;
        p = atomicAdd(&cur[d4.x >> 8], 1);
        ebuf[p] = (unsigned int)s4.x | ((unsigned int)(d4.x & 255) << 16);
        p = atomicAdd(&cur[d4.y >> 8], 1);
        ebuf[p] = (unsigned int)s4.y | ((unsigned int)(d4.y & 255) << 16);
        p = atomicAdd(&cur[d4.z >> 8], 1);
        ebuf[p] = (unsigned int)s4.z | ((unsigned int)(d4.z & 255) << 16);
        p = atomicAdd(&cur[d4.w >> 8], 1);
        ebuf[p] = (unsigned int)s4.w | ((unsigned int)(d4.w & 255) << 16);
    }
}

// ---------------- kC: per-bucket node counts + local scan -> counts AND offsets -----
// offsets[node] = boff[bucket] + exclusive_scan_within_bucket  (bucket scan IS the base)
__global__ __launch_bounds__(256) void k_counts_scan(
        const unsigned int* __restrict__ ebuf, const int* __restrict__ boff,
        int* __restrict__ counts, int* __restrict__ offsets) {
    __shared__ int cnt[256];
    __shared__ int s[256];
    const int t = threadIdx.x;
    const int nb = blockIdx.x;
    cnt[t] = 0;
    __syncthreads();
    const int beg = boff[nb];
    const int end = boff[nb + 1];
    for (int e = beg + t; e < end; e += 256)
        atomicAdd(&cnt[ebuf[e] >> 16], 1);
    __syncthreads();
    const int v = cnt[t];
    s[t] = v;
    __syncthreads();
    for (int off = 1; off < 256; off <<= 1) {
        int add = (t >= off) ? s[t - off] : 0;
        __syncthreads();
        s[t] += add;
        __syncthreads();
    }
    const int node = nb * 256 + t;
    if (node < N_NODES) {
        counts[node] = v;
        offsets[node] = beg + (s[t] - v);
    }
}

// ---------------- kD || gemm1: per-bucket CSR placement (LDS-staged) + gemm1 --------
__global__ __launch_bounds__(256) void k_place_gemm1(
        const unsigned int* __restrict__ ebuf, const int* __restrict__ boff,
        const int* __restrict__ offsets, const int* __restrict__ counts,
        unsigned short* __restrict__ csr,
        const float* __restrict__ x, const float* __restrict__ W1,
        _Float16* __restrict__ h1s) {
    __shared__ union {
        float xs[16][IN_DIM];                          // gemm1 role (8 KB)
        struct {
            int offs[256];
            int rank[256];
            unsigned short sbuf[SBUF_CAP];
        } p;                                           // place role (14 KB)
    } sm;
    const int bid = blockIdx.x;
    if (bid < NBUCK) {
        // ---- placement role ----
        const int nb = bid;
        const int nbase = nb * 256;
        const int ebeg = boff[nb];
        const int eend = boff[nb + 1];
        const int seglen = eend - ebeg;
        const int cbase = ebeg;            // offsets[nbase] == boff[nb]
        {
            const int node = nbase + threadIdx.x;
            sm.p.offs[threadIdx.x] = ((node < N_NODES) ? offsets[node] : eend) - cbase;
            sm.p.rank[threadIdx.x] = 0;
        }
        __syncthreads();
        const bool staged = (seglen <= SBUF_CAP);
        for (int e = ebeg + threadIdx.x; e < eend; e += 256) {
            const unsigned int u = ebuf[e];
            const unsigned short sv = (unsigned short)(u & 0xFFFF);
            const int dl = (int)(u >> 16);
            const int r = atomicAdd(&sm.p.rank[dl], 1);
            const int lp = sm.p.offs[dl] + r;
            if (staged) sm.p.sbuf[lp] = sv;
            else        csr[cbase + lp] = sv;
        }
        __syncthreads();
        if (staged) {
            for (int i = threadIdx.x; i < seglen; i += 256)
                csr[cbase + i] = sm.p.sbuf[i];
        }
        return;
    }
    // ---- gemm1 role: 16 nodes/block, 4 nodes/thread; dinv computed on the fly ----
    const int t = threadIdx.x;
    const int wave = t >> 6;
    const int lane = t & 63;
    const long base = (long)(bid - NBUCK) * 16;
    {
        float4* xsv = reinterpret_cast<float4*>(&sm.xs[0][0]);
        const float4* xv = reinterpret_cast<const float4*>(&x[base * IN_DIM]);
        xsv[t]       = xv[t];
        xsv[t + 256] = xv[t + 256];
    }
    __syncthreads();
    const int n0 = wave * 4, n1 = n0 + 1, n2 = n0 + 2, n3 = n0 + 3;
    float a0 = 0.f, a1 = 0.f, a2 = 0.f, a3 = 0.f;
#pragma unroll 8
    for (int k = 0; k < IN_DIM; ++k) {
        const float wv = W1[k * HID_DIM + lane];
        a0 = fmaf(sm.xs[n0][k], wv, a0);
        a1 = fmaf(sm.xs[n1][k], wv, a1);
        a2 = fmaf(sm.xs[n2][k], wv, a2);
        a3 = fmaf(sm.xs[n3][k], wv, a3);
    }
    const float d0 = rsqrtf((float)(counts[base + n0] + 1));
    const float d1 = rsqrtf((float)(counts[base + n1] + 1));
    const float d2 = rsqrtf((float)(counts[base + n2] + 1));
    const float d3 = rsqrtf((float)(counts[base + n3] + 1));
    h1s[(base + n0) * HID_DIM + lane] = (_Float16)(a0 * d0);
    h1s[(base + n1) * HID_DIM + lane] = (_Float16)(a1 * d1);
    h1s[(base + n2) * HID_DIM + lane] = (_Float16)(a2 * d2);
    h1s[(base + n3) * HID_DIM + lane] = (_Float16)(a3 * d3);
}

// ---------------- gather core: one 16-lane group owns one node, 8-deep pipeline ------
__device__ __forceinline__ float4 gather_node(
        const unsigned short* __restrict__ csr, const _Float16* __restrict__ h,
        int n, int beg, int cnt, int sub) {
    float4 a0 = {0,0,0,0}, a1 = {0,0,0,0}, a2 = {0,0,0,0}, a3 = {0,0,0,0};
    int e = 0;
    for (; e + 8 <= cnt; e += 8) {
        int idx[8];
#pragma unroll
        for (int j = 0; j < 8; ++j) idx[j] = csr[beg + e + j];
        half4v v[8];
#pragma unroll
        for (int j = 0; j < 8; ++j)
            v[j] = *reinterpret_cast<const half4v*>(&h[(long)idx[j] * 64 + sub * 4]);
        f4addh(a0, v[0]); f4addh(a1, v[1]); f4addh(a2, v[2]); f4addh(a3, v[3]);
        f4addh(a0, v[4]); f4addh(a1, v[5]); f4addh(a2, v[6]); f4addh(a3, v[7]);
    }
    if (e + 4 <= cnt) {
        int idx[4];
#pragma unroll
        for (int j = 0; j < 4; ++j) idx[j] = csr[beg + e + j];
        half4v v[4];
#pragma unroll
        for (int j = 0; j < 4; ++j)
            v[j] = *reinterpret_cast<const half4v*>(&h[(long)idx[j] * 64 + sub * 4]);
        f4addh(a0, v[0]); f4addh(a1, v[1]); f4addh(a2, v[2]); f4addh(a3, v[3]);
        e += 4;
    }
    for (; e < cnt; ++e)
        f4addh(a0, *reinterpret_cast<const half4v*>(&h[(long)csr[beg + e] * 64 + sub * 4]));
    f4addh(a1, *reinterpret_cast<const half4v*>(&h[(long)n * 64 + sub * 4]));  // self-loop
    float4 a;
    a.x = (a0.x + a1.x) + (a2.x + a3.x);
    a.y = (a0.y + a1.y) + (a2.y + a3.y);
    a.z = (a0.z + a1.z) + (a2.z + a3.z);
    a.w = (a0.w + a1.w) + (a2.w + a3.w);
    return a;
}

// ---------------- fused: agg layer1 + bias + ReLU + GEMM2 + pre-scale ---------------
__global__ __launch_bounds__(256) void k_agg1_fused(
        const unsigned short* __restrict__ csr, const int* __restrict__ offsets,
        const int* __restrict__ counts,
        const _Float16* __restrict__ h1s, const float* __restrict__ b1,
        const float* __restrict__ W2, _Float16* __restrict__ h3s) {
    __shared__ float rs[16][HID_DIM];   // 4 KB
    __shared__ float dis[16];
    const int g = threadIdx.x >> 4;
    const int sub = threadIdx.x & 15;
    const long nbase = (long)blockIdx.x * 16;
    const int n = (int)nbase + g;
    const int beg = offsets[n];
    const int cnt = counts[n];
    float4 a = gather_node(csr, h1s, n, beg, cnt, sub);
    const float di = rsqrtf((float)(cnt + 1));
    if (sub == 0) dis[g] = di;
    const float4 bv = *reinterpret_cast<const float4*>(&b1[sub * 4]);
    float4 r;
    r.x = fmaxf(a.x * di + bv.x, 0.0f);
    r.y = fmaxf(a.y * di + bv.y, 0.0f);
    r.z = fmaxf(a.z * di + bv.z, 0.0f);
    r.w = fmaxf(a.w * di + bv.w, 0.0f);
    *reinterpret_cast<float4*>(&rs[g][sub * 4]) = r;
    __syncthreads();
    // GEMM phase: wave w computes nodes 4w..4w+3
    const int wave = threadIdx.x >> 6;
    const int lane = threadIdx.x & 63;
    float acc[4] = {0.f, 0.f, 0.f, 0.f};
#pragma unroll 4
    for (int k = 0; k < HID_DIM; ++k) {
        const float wv = W2[k * OUT_DIM + lane];
#pragma unroll
        for (int m = 0; m < 4; ++m)
            acc[m] = fmaf(rs[wave * 4 + m][k], wv, acc[m]);
    }
#pragma unroll
    for (int m = 0; m < 4; ++m) {
        const long node = nbase + wave * 4 + m;
        h3s[node * 64 + lane] = (_Float16)(acc[m] * dis[wave * 4 + m]);
    }
}

// ---------------- final aggregation (non-temporal dout stores) ----------------------
__global__ __launch_bounds__(256) void k_agg2(
        const unsigned short* __restrict__ csr, const int* __restrict__ offsets,
        const int* __restrict__ counts,
        const _Float16* __restrict__ h3s, const float* __restrict__ b2,
        float* __restrict__ dout) {
    const int g = threadIdx.x >> 4;
    const int sub = threadIdx.x & 15;
    const int n = blockIdx.x * 16 + g;
    const int beg = offsets[n];
    const int cnt = counts[n];
    float4 a = gather_node(csr, h3s, n, beg, cnt, sub);
    const float di = rsqrtf((float)(cnt + 1));
    const float4 bv = *reinterpret_cast<const float4*>(&b2[sub * 4]);
    float4v r;
    r.x = a.x * di + bv.x;
    r.y = a.y * di + bv.y;
    r.z = a.z * di + bv.z;
    r.w = a.w * di + bv.w;
    __builtin_nontemporal_store(r, reinterpret_cast<float4v*>(&dout[(long)n * 64 + sub * 4]));
}

extern "C" void kernel_launch(void* const* d_in, const int* in_sizes, int n_in,
                              void* d_out, int out_size, void* d_ws, size_t ws_size,
                              hipStream_t stream) {
    const float* x  = (const float*)d_in[0];
    const int*   ei = (const int*)d_in[1];          // [2, N_EDGES]
    const float* W1 = (const float*)d_in[2];
    const float* b1 = (const float*)d_in[3];
    const float* W2 = (const float*)d_in[4];
    const float* b2 = (const float*)d_in[5];
    float* dout = (float*)d_out;

    const int* src = ei;
    const int* dst = ei + N_EDGES;

    char* w = (char*)d_ws;
    int*            counts   = (int*)w;            w += 50176 * 4;
    int*            offsets  = (int*)w;            w += 50176 * 4;
    int*            bcnt     = (int*)w;            w += 256 * 4;
    int*            boff     = (int*)w;            w += 256 * 4;
    int*            bcur     = (int*)w;            w += 256 * 4;
    unsigned int*   ebuf     = (unsigned int*)w;   w += (long)N_EDGES * 4;
    unsigned short* csr      = (unsigned short*)w; w += (long)N_EDGES * 2;
    _Float16*       h1s      = (_Float16*)w;       w += (long)N_NODES * 64 * 2;
    _Float16*       h3s      = (_Float16*)w;

    // CSR build via two-level LDS counting sort (no fine-grained global atomics)
    k_zero_buckets<<<1, 256, 0, stream>>>(bcnt);
    k_bucket_histo<<<EDGE_BLOCKS, 256, 0, stream>>>(dst, bcnt);
    k_scan_buckets<<<1, 256, 0, stream>>>(bcnt, boff, bcur);
    k_bucket_scatter<<<EDGE_BLOCKS, 256, 0, stream>>>(src, dst, bcur, ebuf);
    k_counts_scan<<<NBUCK, 256, 0, stream>>>(ebuf, boff, counts, offsets);

    k_place_gemm1<<<NBUCK + GEMM1_BLOCKS, 256, 0, stream>>>(
        ebuf, boff, offsets, counts, csr, x, W1, h1s);

    k_agg1_fused<<<AGG_BLOCKS, 256, 0, stream>>>(csr, offsets, counts, h1s, b1, W2, h3s);
    k_agg2<<<AGG_BLOCKS, 256, 0, stream>>>(csr, offsets, counts, h3s, b2, dout);
}